// Round 1
// baseline (2057.017 us; speedup 1.0000x reference)
//
#include <hip/hip_runtime.h>
#include <cstddef>

#define N_NODES 65536
#define NPER    1024
#define NGRAPH  64
#define HID     64
#define IN_F    128
#define KCLUS   16
#define NCLS    10

// ---------------------------------------------------------------- degree
__global__ void deg_kernel(const int* __restrict__ dst, int* __restrict__ deg, int E) {
    int e = blockIdx.x * blockDim.x + threadIdx.x;
    if (e < E) atomicAdd(&deg[dst[e]], 1);
}

__global__ void dinv_kernel(const int* __restrict__ deg, float* __restrict__ dinv, int n) {
    int i = blockIdx.x * blockDim.x + threadIdx.x;
    if (i < n) dinv[i] = rsqrtf((float)deg[i] + 1.0f);
}

// ---------------------------------------------------------------- dense linear: Y[N,64] = X[N,K] @ W[64,K]^T
// Block: 256 threads, 64 rows x 64 cols tile, 4x4 register blocking.
template <int K>
__global__ __launch_bounds__(256) void linear_kernel(const float* __restrict__ X,
                                                     const float* __restrict__ W,
                                                     float* __restrict__ Y) {
    __shared__ float xs[64][K + 1];
    __shared__ float ws[HID][K + 1];
    const int t = threadIdx.x;
    const size_t row0 = (size_t)blockIdx.x * 64;

    for (int i = t; i < HID * K; i += 256) ws[i / K][i % K] = W[i];
    for (int i = t; i < 64 * K; i += 256) xs[i / K][i % K] = X[row0 * K + i];
    __syncthreads();

    const int r0 = (t >> 4) * 4;   // 16 row-groups
    const int c0 = (t & 15) * 4;   // 16 col-groups
    float acc[4][4] = {};

#pragma unroll 4
    for (int k = 0; k < K; ++k) {
        float xv0 = xs[r0 + 0][k], xv1 = xs[r0 + 1][k];
        float xv2 = xs[r0 + 2][k], xv3 = xs[r0 + 3][k];
        float wv0 = ws[c0 + 0][k], wv1 = ws[c0 + 1][k];
        float wv2 = ws[c0 + 2][k], wv3 = ws[c0 + 3][k];
        acc[0][0] = fmaf(xv0, wv0, acc[0][0]);
        acc[0][1] = fmaf(xv0, wv1, acc[0][1]);
        acc[0][2] = fmaf(xv0, wv2, acc[0][2]);
        acc[0][3] = fmaf(xv0, wv3, acc[0][3]);
        acc[1][0] = fmaf(xv1, wv0, acc[1][0]);
        acc[1][1] = fmaf(xv1, wv1, acc[1][1]);
        acc[1][2] = fmaf(xv1, wv2, acc[1][2]);
        acc[1][3] = fmaf(xv1, wv3, acc[1][3]);
        acc[2][0] = fmaf(xv2, wv0, acc[2][0]);
        acc[2][1] = fmaf(xv2, wv1, acc[2][1]);
        acc[2][2] = fmaf(xv2, wv2, acc[2][2]);
        acc[2][3] = fmaf(xv2, wv3, acc[2][3]);
        acc[3][0] = fmaf(xv3, wv0, acc[3][0]);
        acc[3][1] = fmaf(xv3, wv1, acc[3][1]);
        acc[3][2] = fmaf(xv3, wv2, acc[3][2]);
        acc[3][3] = fmaf(xv3, wv3, acc[3][3]);
    }

#pragma unroll
    for (int i = 0; i < 4; ++i) {
        float4 v = make_float4(acc[i][0], acc[i][1], acc[i][2], acc[i][3]);
        *(float4*)(Y + (row0 + r0 + i) * HID + c0) = v;
    }
}

// ---------------------------------------------------------------- edge scatter-add
// 16 threads per edge, each handles 4 consecutive features (float4 gather).
__global__ void edge_agg_kernel(const int* __restrict__ src, const int* __restrict__ dst,
                                const float* __restrict__ dinv, const float* __restrict__ h,
                                float* __restrict__ agg, int E) {
    long long gt = (long long)blockIdx.x * blockDim.x + threadIdx.x;
    int e = (int)(gt >> 4);
    int f = ((int)gt & 15) << 2;
    if (e < E) {
        int s = src[e], d = dst[e];
        float c = dinv[s] * dinv[d];
        const float4 hv = *(const float4*)(h + (size_t)s * HID + f);
        float* ap = agg + (size_t)d * HID + f;
        unsafeAtomicAdd(ap + 0, hv.x * c);
        unsafeAtomicAdd(ap + 1, hv.y * c);
        unsafeAtomicAdd(ap + 2, hv.z * c);
        unsafeAtomicAdd(ap + 3, hv.w * c);
    }
}

// ---------------------------------------------------------------- self-loop + bias + relu (in place on agg)
__global__ void selfloop_relu_kernel(float* __restrict__ agg, const float* __restrict__ h,
                                     const float* __restrict__ dinv, const float* __restrict__ bias,
                                     int total) {
    int i = blockIdx.x * blockDim.x + threadIdx.x;
    if (i < total) {
        int row = i >> 6, col = i & 63;
        float dv = dinv[row];
        float v = agg[i] + h[i] * dv * dv + bias[col];
        agg[i] = v > 0.f ? v : 0.f;
    }
}

// ---------------------------------------------------------------- DMoN assignment: s = softmax(h @ Wp^T + bp)
__global__ __launch_bounds__(256) void assign_kernel(const float* __restrict__ h,
                                                     const float* __restrict__ Wp,
                                                     const float* __restrict__ bp,
                                                     float* __restrict__ s) {
    __shared__ float hs[256][65];
    __shared__ float wp[KCLUS][HID];
    __shared__ float bps[KCLUS];
    const int t = threadIdx.x;
    const size_t node0 = (size_t)blockIdx.x * 256;

    for (int i = t; i < 256 * HID; i += 256) hs[i >> 6][i & 63] = h[node0 * HID + i];
    for (int i = t; i < KCLUS * HID; i += 256) wp[i >> 6][i & 63] = Wp[i];
    if (t < KCLUS) bps[t] = bp[t];
    __syncthreads();

    float lg[KCLUS];
    float mx = -1e30f;
#pragma unroll
    for (int k = 0; k < KCLUS; ++k) {
        float a = bps[k];
#pragma unroll 8
        for (int hh = 0; hh < HID; ++hh) a = fmaf(hs[t][hh], wp[k][hh], a);
        lg[k] = a;
        mx = fmaxf(mx, a);
    }
    float sum = 0.f;
#pragma unroll
    for (int k = 0; k < KCLUS; ++k) {
        lg[k] = __expf(lg[k] - mx);
        sum += lg[k];
    }
    float inv = 1.0f / sum;
    float4* sp = (float4*)(s + (node0 + t) * KCLUS);
#pragma unroll
    for (int k = 0; k < KCLUS; k += 4)
        sp[k >> 2] = make_float4(lg[k] * inv, lg[k + 1] * inv, lg[k + 2] * inv, lg[k + 3] * inv);
}

// ---------------------------------------------------------------- per-graph pool: Xp = selu(s^T @ Xb); mean_k; @ Wl^T + bl
__global__ __launch_bounds__(256) void pool_kernel(const float* __restrict__ h,
                                                   const float* __restrict__ s,
                                                   const float* __restrict__ Wl,
                                                   const float* __restrict__ bl,
                                                   float* __restrict__ out) {
    __shared__ float xs[256][65];
    __shared__ float ss[256][17];
    __shared__ float xp[KCLUS][65];
    __shared__ float outm[HID];
    const int b = blockIdx.x;
    const int t = threadIdx.x;
    const float* hb = h + (size_t)b * NPER * HID;
    const float* sb = s + (size_t)b * NPER * KCLUS;
    const int hcol = t & 63;
    const int k0 = (t >> 6) * 4;

    float acc0 = 0.f, acc1 = 0.f, acc2 = 0.f, acc3 = 0.f;
    for (int chunk = 0; chunk < NPER / 256; ++chunk) {
        __syncthreads();
        const int nb = chunk * 256;
        for (int i = t; i < 256 * HID; i += 256) xs[i >> 6][i & 63] = hb[(size_t)nb * HID + i];
        for (int i = t; i < 256 * KCLUS; i += 256) ss[i >> 4][i & 15] = sb[(size_t)nb * KCLUS + i];
        __syncthreads();
#pragma unroll 8
        for (int n = 0; n < 256; ++n) {
            float xv = xs[n][hcol];
            acc0 = fmaf(ss[n][k0 + 0], xv, acc0);
            acc1 = fmaf(ss[n][k0 + 1], xv, acc1);
            acc2 = fmaf(ss[n][k0 + 2], xv, acc2);
            acc3 = fmaf(ss[n][k0 + 3], xv, acc3);
        }
    }

    const float sc = 1.0507009873554805f, al = 1.6732632423543772f;
    auto selu = [&](float v) { return v > 0.f ? sc * v : sc * al * (__expf(v) - 1.f); };
    xp[k0 + 0][hcol] = selu(acc0);
    xp[k0 + 1][hcol] = selu(acc1);
    xp[k0 + 2][hcol] = selu(acc2);
    xp[k0 + 3][hcol] = selu(acc3);
    __syncthreads();

    if (t < HID) {
        float m = 0.f;
#pragma unroll
        for (int k = 0; k < KCLUS; ++k) m += xp[k][t];
        outm[t] = m * (1.0f / KCLUS);
    }
    __syncthreads();

    if (t < NCLS) {
        float a = bl[t];
#pragma unroll 8
        for (int hh = 0; hh < HID; ++hh) a = fmaf(outm[hh], Wl[t * HID + hh], a);
        out[b * NCLS + t] = a;
    }
}

// ---------------------------------------------------------------- launch
extern "C" void kernel_launch(void* const* d_in, const int* in_sizes, int n_in,
                              void* d_out, int out_size, void* d_ws, size_t ws_size,
                              hipStream_t stream) {
    const float* x  = (const float*)d_in[0];
    const int* eidx = (const int*)d_in[1];
    const float* W1 = (const float*)d_in[3];
    const float* b1 = (const float*)d_in[4];
    const float* W2 = (const float*)d_in[5];
    const float* b2 = (const float*)d_in[6];
    const float* Wp = (const float*)d_in[7];
    const float* bp = (const float*)d_in[8];
    const float* Wl = (const float*)d_in[9];
    const float* bl = (const float*)d_in[10];
    float* out = (float*)d_out;

    const int E = in_sizes[1] / 2;
    const int* src = eidx;
    const int* dst = eidx + E;

    // workspace layout (all 4-byte types): deg | dinv | A | B | S
    char* w = (char*)d_ws;
    int*   deg  = (int*)w;     w += (size_t)N_NODES * 4;
    float* dinv = (float*)w;   w += (size_t)N_NODES * 4;
    float* A    = (float*)w;   w += (size_t)N_NODES * HID * 4;   // gemm output / gather source
    float* Bf   = (float*)w;   w += (size_t)N_NODES * HID * 4;   // agg accumulator / activations
    float* S    = (float*)w;   w += (size_t)N_NODES * KCLUS * 4; // softmax assignments

    hipMemsetAsync(deg, 0, (size_t)N_NODES * 4, stream);
    deg_kernel<<<(E + 255) / 256, 256, 0, stream>>>(dst, deg, E);
    dinv_kernel<<<N_NODES / 256, 256, 0, stream>>>(deg, dinv, N_NODES);

    // conv1: A = x @ W1^T ; B = scatter(A) + self + b1, relu
    linear_kernel<IN_F><<<N_NODES / 64, 256, 0, stream>>>(x, W1, A);
    hipMemsetAsync(Bf, 0, (size_t)N_NODES * HID * 4, stream);
    edge_agg_kernel<<<(int)(((long long)E * 16) / 256), 256, 0, stream>>>(src, dst, dinv, A, Bf, E);
    selfloop_relu_kernel<<<N_NODES * HID / 256, 256, 0, stream>>>(Bf, A, dinv, b1, N_NODES * HID);

    // conv2: A = B @ W2^T ; B = scatter(A) + self + b2, relu
    linear_kernel<HID><<<N_NODES / 64, 256, 0, stream>>>(Bf, W2, A);
    hipMemsetAsync(Bf, 0, (size_t)N_NODES * HID * 4, stream);
    edge_agg_kernel<<<(int)(((long long)E * 16) / 256), 256, 0, stream>>>(src, dst, dinv, A, Bf, E);
    selfloop_relu_kernel<<<N_NODES * HID / 256, 256, 0, stream>>>(Bf, A, dinv, b2, N_NODES * HID);

    // DMoN pooling + classifier
    assign_kernel<<<N_NODES / 256, 256, 0, stream>>>(Bf, Wp, bp, S);
    pool_kernel<<<NGRAPH, 256, 0, stream>>>(Bf, S, Wl, bl, out);
}

// Round 2
// 392.045 us; speedup vs baseline: 5.2469x; 5.2469x over previous
//
#include <hip/hip_runtime.h>
#include <cstddef>

#define N_NODES 65536
#define NPER    1024
#define NGRAPH  64
#define HID     64
#define IN_F    128
#define KCLUS   16
#define NCLS    10

// ---------------------------------------------------------------- degree histogram (in-degree per dst)
__global__ void deg_kernel(const int* __restrict__ dst, int* __restrict__ deg, int E) {
    int e = blockIdx.x * blockDim.x + threadIdx.x;
    if (e < E) atomicAdd(&deg[dst[e]], 1);
}

__global__ void dinv_kernel(const int* __restrict__ deg, float* __restrict__ dinv, int n) {
    int i = blockIdx.x * blockDim.x + threadIdx.x;
    if (i < n) dinv[i] = rsqrtf((float)deg[i] + 1.0f);
}

// ---------------------------------------------------------------- per-graph exclusive scan of deg -> rp, graph totals -> gsum
__global__ __launch_bounds__(256) void scan_graph_kernel(const int* __restrict__ deg,
                                                         int* __restrict__ rp,
                                                         int* __restrict__ gsum) {
    __shared__ int ts[256];
    const int g = blockIdx.x, t = threadIdx.x;
    const int* dg = deg + (size_t)g * NPER;
    int4 v = *(const int4*)(dg + t * 4);
    int s0 = v.x, s1 = s0 + v.y, s2 = s1 + v.z, s3 = s2 + v.w;
    ts[t] = s3;
    __syncthreads();
    // Hillis-Steele inclusive scan over 256 thread sums
    for (int off = 1; off < 256; off <<= 1) {
        int x = (t >= off) ? ts[t - off] : 0;
        __syncthreads();
        ts[t] += x;
        __syncthreads();
    }
    int excl = (t > 0) ? ts[t - 1] : 0;
    int4 o;
    o.x = excl; o.y = excl + s0; o.z = excl + s1; o.w = excl + s2;
    *(int4*)(rp + (size_t)g * NPER + t * 4) = o;
    if (t == 255) gsum[g] = ts[255];
}

__global__ void scan_gsum_kernel(const int* __restrict__ gsum, int* __restrict__ gbase) {
    if (threadIdx.x == 0 && blockIdx.x == 0) {
        int acc = 0;
        for (int g = 0; g < NGRAPH; ++g) { gbase[g] = acc; acc += gsum[g]; }
    }
}

// ---------------------------------------------------------------- scatter edges into CSR (sorted by dst)
__global__ void scatter_kernel(const int* __restrict__ src, const int* __restrict__ dst,
                               const int* __restrict__ rp, const int* __restrict__ gbase,
                               int* __restrict__ cur, int* __restrict__ esrc, int E) {
    int e = blockIdx.x * blockDim.x + threadIdx.x;
    if (e < E) {
        int d = dst[e];
        int pos = gbase[d >> 10] + rp[d] + atomicAdd(&cur[d], 1);
        esrc[pos] = src[e];
    }
}

// ---------------------------------------------------------------- dense linear: Y[N,64] = X[N,K] @ W[64,K]^T
template <int K>
__global__ __launch_bounds__(256) void linear_kernel(const float* __restrict__ X,
                                                     const float* __restrict__ W,
                                                     float* __restrict__ Y) {
    __shared__ float xs[64][K + 1];
    __shared__ float ws[HID][K + 1];
    const int t = threadIdx.x;
    const size_t row0 = (size_t)blockIdx.x * 64;

    for (int i = t; i < HID * K; i += 256) ws[i / K][i % K] = W[i];
    for (int i = t; i < 64 * K; i += 256) xs[i / K][i % K] = X[row0 * K + i];
    __syncthreads();

    const int r0 = (t >> 4) * 4;
    const int c0 = (t & 15) * 4;
    float acc[4][4] = {};

#pragma unroll 4
    for (int k = 0; k < K; ++k) {
        float xv0 = xs[r0 + 0][k], xv1 = xs[r0 + 1][k];
        float xv2 = xs[r0 + 2][k], xv3 = xs[r0 + 3][k];
        float wv0 = ws[c0 + 0][k], wv1 = ws[c0 + 1][k];
        float wv2 = ws[c0 + 2][k], wv3 = ws[c0 + 3][k];
        acc[0][0] = fmaf(xv0, wv0, acc[0][0]);
        acc[0][1] = fmaf(xv0, wv1, acc[0][1]);
        acc[0][2] = fmaf(xv0, wv2, acc[0][2]);
        acc[0][3] = fmaf(xv0, wv3, acc[0][3]);
        acc[1][0] = fmaf(xv1, wv0, acc[1][0]);
        acc[1][1] = fmaf(xv1, wv1, acc[1][1]);
        acc[1][2] = fmaf(xv1, wv2, acc[1][2]);
        acc[1][3] = fmaf(xv1, wv3, acc[1][3]);
        acc[2][0] = fmaf(xv2, wv0, acc[2][0]);
        acc[2][1] = fmaf(xv2, wv1, acc[2][1]);
        acc[2][2] = fmaf(xv2, wv2, acc[2][2]);
        acc[2][3] = fmaf(xv2, wv3, acc[2][3]);
        acc[3][0] = fmaf(xv3, wv0, acc[3][0]);
        acc[3][1] = fmaf(xv3, wv1, acc[3][1]);
        acc[3][2] = fmaf(xv3, wv2, acc[3][2]);
        acc[3][3] = fmaf(xv3, wv3, acc[3][3]);
    }

#pragma unroll
    for (int i = 0; i < 4; ++i) {
        float4 v = make_float4(acc[i][0], acc[i][1], acc[i][2], acc[i][3]);
        *(float4*)(Y + (row0 + r0 + i) * HID + c0) = v;
    }
}

// ---------------------------------------------------------------- pull-based aggregation, fused self-loop+bias+relu
// grid = NGRAPH * 8 blocks; block (g, fq) handles feats [fq*8, fq*8+8) of graph g.
// LDS holds Hs[j][s] = h[g*1024+s][f0+j] * dinv[s]  (transposed, stride 1025 -> conflict-free staging).
__global__ __launch_bounds__(256) void agg_kernel(const float* __restrict__ h,
                                                  const int* __restrict__ esrc,
                                                  const int* __restrict__ rp,
                                                  const int* __restrict__ gbase,
                                                  const int* __restrict__ deg,
                                                  const float* __restrict__ dinv,
                                                  const float* __restrict__ bias,
                                                  float* __restrict__ outp) {
    __shared__ float Hs[8][NPER + 1];
    __shared__ float dl[NPER];
    const int g = blockIdx.x >> 3;
    const int f0 = (blockIdx.x & 7) * 8;
    const int t = threadIdx.x;
    const int base = g * NPER;

    for (int r = t; r < NPER; r += 256) {
        const float* hp = h + (size_t)(base + r) * HID + f0;
        float4 a = *(const float4*)hp;
        float4 b = *(const float4*)(hp + 4);
        float dv = dinv[base + r];
        dl[r] = dv;
        Hs[0][r] = a.x * dv; Hs[1][r] = a.y * dv; Hs[2][r] = a.z * dv; Hs[3][r] = a.w * dv;
        Hs[4][r] = b.x * dv; Hs[5][r] = b.y * dv; Hs[6][r] = b.z * dv; Hs[7][r] = b.w * dv;
    }
    float bb[8];
#pragma unroll
    for (int j = 0; j < 8; ++j) bb[j] = bias[f0 + j];
    const int gb = gbase[g];
    __syncthreads();

    for (int ld = t; ld < NPER; ld += 256) {
        const int d = base + ld;
        int p = gb + rp[d];
        const int pe = p + deg[d];
        float acc[8];
#pragma unroll
        for (int j = 0; j < 8; ++j) acc[j] = Hs[j][ld];  // self-loop term (already * dinv[self])
        for (; p < pe; ++p) {
            int sl = esrc[p] - base;
#pragma unroll
            for (int j = 0; j < 8; ++j) acc[j] += Hs[j][sl];
        }
        const float dv = dl[ld];
        float4 o0, o1;
        o0.x = fmaxf(fmaf(acc[0], dv, bb[0]), 0.f);
        o0.y = fmaxf(fmaf(acc[1], dv, bb[1]), 0.f);
        o0.z = fmaxf(fmaf(acc[2], dv, bb[2]), 0.f);
        o0.w = fmaxf(fmaf(acc[3], dv, bb[3]), 0.f);
        o1.x = fmaxf(fmaf(acc[4], dv, bb[4]), 0.f);
        o1.y = fmaxf(fmaf(acc[5], dv, bb[5]), 0.f);
        o1.z = fmaxf(fmaf(acc[6], dv, bb[6]), 0.f);
        o1.w = fmaxf(fmaf(acc[7], dv, bb[7]), 0.f);
        float* op = outp + (size_t)d * HID + f0;
        *(float4*)op = o0;
        *(float4*)(op + 4) = o1;
    }
}

// ---------------------------------------------------------------- DMoN assignment: s = softmax(h @ Wp^T + bp)
__global__ __launch_bounds__(256) void assign_kernel(const float* __restrict__ h,
                                                     const float* __restrict__ Wp,
                                                     const float* __restrict__ bp,
                                                     float* __restrict__ s) {
    __shared__ float hs[256][65];
    __shared__ float wp[KCLUS][HID];
    __shared__ float bps[KCLUS];
    const int t = threadIdx.x;
    const size_t node0 = (size_t)blockIdx.x * 256;

    for (int i = t; i < 256 * HID; i += 256) hs[i >> 6][i & 63] = h[node0 * HID + i];
    for (int i = t; i < KCLUS * HID; i += 256) wp[i >> 6][i & 63] = Wp[i];
    if (t < KCLUS) bps[t] = bp[t];
    __syncthreads();

    float lg[KCLUS];
    float mx = -1e30f;
#pragma unroll
    for (int k = 0; k < KCLUS; ++k) {
        float a = bps[k];
#pragma unroll 8
        for (int hh = 0; hh < HID; ++hh) a = fmaf(hs[t][hh], wp[k][hh], a);
        lg[k] = a;
        mx = fmaxf(mx, a);
    }
    float sum = 0.f;
#pragma unroll
    for (int k = 0; k < KCLUS; ++k) {
        lg[k] = __expf(lg[k] - mx);
        sum += lg[k];
    }
    float inv = 1.0f / sum;
    float4* sp = (float4*)(s + (node0 + t) * KCLUS);
#pragma unroll
    for (int k = 0; k < KCLUS; k += 4)
        sp[k >> 2] = make_float4(lg[k] * inv, lg[k + 1] * inv, lg[k + 2] * inv, lg[k + 3] * inv);
}

// ---------------------------------------------------------------- per-graph pool: Xp = selu(s^T @ Xb); mean_k; @ Wl^T + bl
__global__ __launch_bounds__(256) void pool_kernel(const float* __restrict__ h,
                                                   const float* __restrict__ s,
                                                   const float* __restrict__ Wl,
                                                   const float* __restrict__ bl,
                                                   float* __restrict__ out) {
    __shared__ float xs[256][65];
    __shared__ float ss[256][17];
    __shared__ float xp[KCLUS][65];
    __shared__ float outm[HID];
    const int b = blockIdx.x;
    const int t = threadIdx.x;
    const float* hb = h + (size_t)b * NPER * HID;
    const float* sb = s + (size_t)b * NPER * KCLUS;
    const int hcol = t & 63;
    const int k0 = (t >> 6) * 4;

    float acc0 = 0.f, acc1 = 0.f, acc2 = 0.f, acc3 = 0.f;
    for (int chunk = 0; chunk < NPER / 256; ++chunk) {
        __syncthreads();
        const int nb = chunk * 256;
        for (int i = t; i < 256 * HID; i += 256) xs[i >> 6][i & 63] = hb[(size_t)nb * HID + i];
        for (int i = t; i < 256 * KCLUS; i += 256) ss[i >> 4][i & 15] = sb[(size_t)nb * KCLUS + i];
        __syncthreads();
#pragma unroll 8
        for (int n = 0; n < 256; ++n) {
            float xv = xs[n][hcol];
            acc0 = fmaf(ss[n][k0 + 0], xv, acc0);
            acc1 = fmaf(ss[n][k0 + 1], xv, acc1);
            acc2 = fmaf(ss[n][k0 + 2], xv, acc2);
            acc3 = fmaf(ss[n][k0 + 3], xv, acc3);
        }
    }

    const float sc = 1.0507009873554805f, al = 1.6732632423543772f;
    auto selu = [&](float v) { return v > 0.f ? sc * v : sc * al * (__expf(v) - 1.f); };
    xp[k0 + 0][hcol] = selu(acc0);
    xp[k0 + 1][hcol] = selu(acc1);
    xp[k0 + 2][hcol] = selu(acc2);
    xp[k0 + 3][hcol] = selu(acc3);
    __syncthreads();

    if (t < HID) {
        float m = 0.f;
#pragma unroll
        for (int k = 0; k < KCLUS; ++k) m += xp[k][t];
        outm[t] = m * (1.0f / KCLUS);
    }
    __syncthreads();

    if (t < NCLS) {
        float a = bl[t];
#pragma unroll 8
        for (int hh = 0; hh < HID; ++hh) a = fmaf(outm[hh], Wl[t * HID + hh], a);
        out[b * NCLS + t] = a;
    }
}

// ---------------------------------------------------------------- launch
extern "C" void kernel_launch(void* const* d_in, const int* in_sizes, int n_in,
                              void* d_out, int out_size, void* d_ws, size_t ws_size,
                              hipStream_t stream) {
    const float* x  = (const float*)d_in[0];
    const int* eidx = (const int*)d_in[1];
    const float* W1 = (const float*)d_in[3];
    const float* b1 = (const float*)d_in[4];
    const float* W2 = (const float*)d_in[5];
    const float* b2 = (const float*)d_in[6];
    const float* Wp = (const float*)d_in[7];
    const float* bp = (const float*)d_in[8];
    const float* Wl = (const float*)d_in[9];
    const float* bl = (const float*)d_in[10];
    float* out = (float*)d_out;

    const int E = in_sizes[1] / 2;
    const int* src = eidx;
    const int* dst = eidx + E;

    // workspace layout: deg | dinv | rp | cur | gsum | gbase | A | Bf | union(esrc, S)
    char* w = (char*)d_ws;
    int*   deg   = (int*)w;   w += (size_t)N_NODES * 4;
    float* dinv  = (float*)w; w += (size_t)N_NODES * 4;
    int*   rp    = (int*)w;   w += (size_t)N_NODES * 4;
    int*   cur   = (int*)w;   w += (size_t)N_NODES * 4;
    int*   gsum  = (int*)w;   w += 256;
    int*   gbase = (int*)w;   w += 256;
    float* A     = (float*)w; w += (size_t)N_NODES * HID * 4;
    float* Bf    = (float*)w; w += (size_t)N_NODES * HID * 4;
    int*   esrc  = (int*)w;                            // E ints
    float* S     = (float*)w;                          // aliases esrc: S used only after convs

    hipMemsetAsync(deg, 0, (size_t)N_NODES * 4, stream);
    hipMemsetAsync(cur, 0, (size_t)N_NODES * 4, stream);

    // CSR build
    deg_kernel<<<(E + 255) / 256, 256, 0, stream>>>(dst, deg, E);
    dinv_kernel<<<N_NODES / 256, 256, 0, stream>>>(deg, dinv, N_NODES);
    scan_graph_kernel<<<NGRAPH, 256, 0, stream>>>(deg, rp, gsum);
    scan_gsum_kernel<<<1, 64, 0, stream>>>(gsum, gbase);
    scatter_kernel<<<(E + 255) / 256, 256, 0, stream>>>(src, dst, rp, gbase, cur, esrc, E);

    // conv1
    linear_kernel<IN_F><<<N_NODES / 64, 256, 0, stream>>>(x, W1, A);
    agg_kernel<<<NGRAPH * 8, 256, 0, stream>>>(A, esrc, rp, gbase, deg, dinv, b1, Bf);

    // conv2
    linear_kernel<HID><<<N_NODES / 64, 256, 0, stream>>>(Bf, W2, A);
    agg_kernel<<<NGRAPH * 8, 256, 0, stream>>>(A, esrc, rp, gbase, deg, dinv, b2, Bf);

    // DMoN pooling + classifier
    assign_kernel<<<N_NODES / 256, 256, 0, stream>>>(Bf, Wp, bp, S);
    pool_kernel<<<NGRAPH, 256, 0, stream>>>(Bf, S, Wl, bl, out);
}